// Round 13
// baseline (273.539 us; speedup 1.0000x reference)
//
#include <hip/hip_runtime.h>
#include <hip/hip_bf16.h>

#define B_ 16
#define T_ 1024
#define D_ 512
#define H_ 8
#define M_ (B_ * T_)

typedef __attribute__((ext_vector_type(4))) float f32x4;
typedef __attribute__((ext_vector_type(8))) short bf16x8;
typedef __attribute__((ext_vector_type(4))) short bf16x4;

__device__ __forceinline__ void gld_lds16(const void* g, void* l) {
    __builtin_amdgcn_global_load_lds((const __attribute__((address_space(1))) void*)g,
                                     (__attribute__((address_space(3))) void*)l, 16, 0, 0);
}

__device__ __forceinline__ short f2bf(float f) {
    union { float f; unsigned u; } v; v.f = f;
    unsigned r = v.u + 0x7FFF + ((v.u >> 16) & 1);
    return (short)(r >> 16);
}

// ---------------- fused prep: wtrans (blocks 0..63) + cvt/masks (blocks 64..4159) ----------
__global__ void prep_kernel(const float* __restrict__ q, const float* __restrict__ k,
                            const float* __restrict__ v,
                            const float* __restrict__ Wq, const float* __restrict__ Wk,
                            const float* __restrict__ Wv,
                            short* __restrict__ Xbf, short* __restrict__ WtAll,
                            float* __restrict__ qm, float* __restrict__ kb) {
    __shared__ float tile[64][65];
    const int t = threadIdx.x;
    const int mat = blockIdx.y;
    if (blockIdx.x < 64) {
        const float* W = (mat == 0) ? Wq : (mat == 1) ? Wk : Wv;
        short* Wt = WtAll + (size_t)mat * D_ * D_;
        const int kt = ((int)blockIdx.x >> 3) * 64;
        const int nt = ((int)blockIdx.x & 7) * 64;
#pragma unroll
        for (int i = 0; i < 4; ++i) {
            int idx = t + i * 256;
            int r = idx >> 4, c4 = idx & 15;
            float4 vv = *(const float4*)&W[(kt + r) * D_ + nt + c4 * 4];
            tile[r][c4 * 4 + 0] = vv.x; tile[r][c4 * 4 + 1] = vv.y;
            tile[r][c4 * 4 + 2] = vv.z; tile[r][c4 * 4 + 3] = vv.w;
        }
        __syncthreads();
#pragma unroll
        for (int i = 0; i < 2; ++i) {
            int idx = t + i * 256;
            int nr = idx >> 3, c8 = idx & 7;
            bf16x8 pk;
#pragma unroll
            for (int j = 0; j < 8; ++j) pk[j] = f2bf(tile[c8 * 8 + j][nr]);
            *(bf16x8*)&Wt[(nt + nr) * D_ + kt + c8 * 8] = pk;
        }
    } else {
        const int w = t >> 6, lane = t & 63;
        const int row = ((int)blockIdx.x - 64) * 4 + w;
        const float* X = (mat == 0) ? q : (mat == 1) ? k : v;
        short* O = Xbf + (size_t)mat * M_ * D_;
        const float4* p = (const float4*)&X[(size_t)row * D_];
        float4 v0 = p[lane], v1 = p[lane + 64];
        float s = v0.x + v0.y + v0.z + v0.w + v1.x + v1.y + v1.z + v1.w;
#pragma unroll
        for (int m = 1; m < 64; m <<= 1) s += __shfl_xor(s, m);
        bf16x4 p0, p1;
        p0[0] = f2bf(v0.x); p0[1] = f2bf(v0.y); p0[2] = f2bf(v0.z); p0[3] = f2bf(v0.w);
        p1[0] = f2bf(v1.x); p1[1] = f2bf(v1.y); p1[2] = f2bf(v1.z); p1[3] = f2bf(v1.w);
        *(bf16x4*)&O[(size_t)row * D_ + lane * 4] = p0;
        *(bf16x4*)&O[(size_t)row * D_ + 256 + lane * 4] = p1;
        if (lane == 0) {
            if (mat == 0) qm[row] = (s != 0.0f) ? 1.0f : 0.0f;
            else if (mat == 1) kb[row] = (s != 0.0f) ? 0.0f : -3e30f;
        }
    }
}

// ---------------- projection GEMM, pure bf16 (m97 structure, gld_lds staging) ----------------
__global__ __launch_bounds__(256) void proj_gemm_bf(
    const short* __restrict__ Xbf, const short* __restrict__ WtAll,
    const float* __restrict__ bq, const float* __restrict__ bk, const float* __restrict__ bv,
    short* __restrict__ QKV, short* __restrict__ VtG) {
    __shared__ char As[16384];
    __shared__ char Bs[16384];
    const int t = threadIdx.x;
    const int u = blockIdx.x;
    const int wgid = (u & 7) * 192 + (u >> 3);
    const int mat = wgid >> 9;
    const int r = wgid & 511;
    const int m0 = (r >> 2) << 7, n0 = (r & 3) << 7;
    const short* X  = Xbf + (size_t)mat * M_ * D_;
    const short* Wt = WtAll + (size_t)mat * D_ * D_;
    const float* bias = (mat == 0) ? bq : (mat == 1) ? bk : bv;
    short* dst = QKV + (size_t)mat * M_ * D_;
    const int lane = t & 63, w = t >> 6;
    const int wr = w >> 1, wc = w & 1;
    const int cl = lane & 15, g = lane >> 4;

    const int r0 = t >> 3, c0 = ((t & 7) ^ (r0 & 7)) * 8;
    const short* sA = X  + (size_t)(m0 + r0) * D_ + c0;
    const short* sB = Wt + (size_t)(n0 + r0) * D_ + c0;

    f32x4 acc[4][4] = {};
#pragma unroll
    for (int i = 0; i < 4; ++i) {
        gld_lds16(sA + (size_t)(32 * i) * D_, As + t * 16 + i * 4096);
        gld_lds16(sB + (size_t)(32 * i) * D_, Bs + t * 16 + i * 4096);
    }
    for (int kt = 0; kt < D_; kt += 64) {
        __syncthreads();
#pragma unroll
        for (int ks = 0; ks < 2; ++ks) {
            bf16x8 a[4], b[4];
#pragma unroll
            for (int m = 0; m < 4; ++m)
                a[m] = *(const bf16x8*)(As + (wr * 64 + m * 16 + cl) * 128 + (((ks * 4 + g) ^ (cl & 7)) << 4));
#pragma unroll
            for (int n = 0; n < 4; ++n)
                b[n] = *(const bf16x8*)(Bs + (wc * 64 + n * 16 + cl) * 128 + (((ks * 4 + g) ^ (cl & 7)) << 4));
#pragma unroll
            for (int m = 0; m < 4; ++m)
#pragma unroll
                for (int n = 0; n < 4; ++n)
                    acc[m][n] = __builtin_amdgcn_mfma_f32_16x16x32_bf16(a[m], b[n], acc[m][n], 0, 0, 0);
        }
        __syncthreads();
        if (kt + 64 < D_) {
            const int k2 = kt + 64;
#pragma unroll
            for (int i = 0; i < 4; ++i) {
                gld_lds16(sA + (size_t)(32 * i) * D_ + k2, As + t * 16 + i * 4096);
                gld_lds16(sB + (size_t)(32 * i) * D_ + k2, Bs + t * 16 + i * 4096);
            }
        }
    }
    if (VtG != nullptr && mat == 2) {
        const int bb = m0 >> 10, tl0 = m0 & 1023;
#pragma unroll
        for (int n = 0; n < 4; ++n) {
            const int col = n0 + wc * 64 + n * 16 + cl;
            const int h = col >> 6, dh = col & 63;
            short* vrow = VtG + ((size_t)(bb * 8 + h) * 64 + dh) * T_;
            const float bv2 = bias[col];
#pragma unroll
            for (int m = 0; m < 4; ++m) {
                const int tl = tl0 + wr * 64 + m * 16 + g * 4;
                bf16x4 pk;
#pragma unroll
                for (int j = 0; j < 4; ++j) pk[j] = f2bf(acc[m][n][j] + bv2);
                *(bf16x4*)&vrow[tl] = pk;
            }
        }
    } else {
#pragma unroll
        for (int n = 0; n < 4; ++n) {
            int col = n0 + wc * 64 + n * 16 + cl;
            float bv2 = bias[col];
#pragma unroll
            for (int m = 0; m < 4; ++m) {
                int rowb = m0 + wr * 64 + m * 16 + g * 4;
#pragma unroll
                for (int j = 0; j < 4; ++j)
                    dst[(size_t)(rowb + j) * D_ + col] = f2bf(acc[m][n][j] + bv2);
            }
        }
    }
}

// ---------------- fallback projection GEMM (fp32 X, in-kernel conversion) ----------------
__global__ __launch_bounds__(256) void proj_gemm(
    const float* __restrict__ Xq, const float* __restrict__ Xk, const float* __restrict__ Xv,
    const short* __restrict__ WtAll,
    const float* __restrict__ bq, const float* __restrict__ bk, const float* __restrict__ bv,
    short* __restrict__ Qb, short* __restrict__ Kb, short* __restrict__ Vb) {
    __shared__ short As2[128][72];
    __shared__ short Bs2[128][72];
    const int t = threadIdx.x;
    const int mat = blockIdx.z;
    const float* X = (mat == 0) ? Xq : (mat == 1) ? Xk : Xv;
    const short* Wt = WtAll + (size_t)mat * D_ * D_;
    const float* bias = (mat == 0) ? bq : (mat == 1) ? bk : bv;
    short* dst = (mat == 0) ? Qb : (mat == 1) ? Kb : Vb;
    const int m0 = blockIdx.x * 128, n0 = blockIdx.y * 128;
    const int lane = t & 63, w = t >> 6;
    const int wr = w >> 1, wc = w & 1;
    const int cl = lane & 15, g = lane >> 4;
    f32x4 acc[4][4] = {};
    for (int kt = 0; kt < D_; kt += 64) {
#pragma unroll
        for (int i = 0; i < 8; ++i) {
            int idx = t + 256 * i;
            int r = idx >> 4, c4 = idx & 15;
            float4 v = *(const float4*)&X[(size_t)(m0 + r) * D_ + kt + c4 * 4];
            bf16x4 pk;
            pk[0] = f2bf(v.x); pk[1] = f2bf(v.y); pk[2] = f2bf(v.z); pk[3] = f2bf(v.w);
            *(bf16x4*)&As2[r][c4 * 4] = pk;
        }
#pragma unroll
        for (int i = 0; i < 4; ++i) {
            int idx = t + 256 * i;
            int r = idx >> 3, c8 = idx & 7;
            *(bf16x8*)&Bs2[r][c8 * 8] = *(const bf16x8*)&Wt[(size_t)(n0 + r) * D_ + kt + c8 * 8];
        }
        __syncthreads();
#pragma unroll
        for (int ks = 0; ks < 2; ++ks) {
            bf16x8 a[4], b[4];
#pragma unroll
            for (int m = 0; m < 4; ++m)
                a[m] = *(const bf16x8*)&As2[wr * 64 + m * 16 + cl][ks * 32 + g * 8];
#pragma unroll
            for (int n = 0; n < 4; ++n)
                b[n] = *(const bf16x8*)&Bs2[wc * 64 + n * 16 + cl][ks * 32 + g * 8];
#pragma unroll
            for (int m = 0; m < 4; ++m)
#pragma unroll
                for (int n = 0; n < 4; ++n)
                    acc[m][n] = __builtin_amdgcn_mfma_f32_16x16x32_bf16(a[m], b[n], acc[m][n], 0, 0, 0);
        }
        __syncthreads();
    }
#pragma unroll
    for (int n = 0; n < 4; ++n) {
        int col = n0 + wc * 64 + n * 16 + cl;
        float bv2 = bias[col];
#pragma unroll
        for (int m = 0; m < 4; ++m) {
            int rowb = m0 + wr * 64 + m * 16 + g * 4;
#pragma unroll
            for (int j = 0; j < 4; ++j)
                dst[(size_t)(rowb + j) * D_ + col] = f2bf(acc[m][n][j] + bv2);
        }
    }
}

// ---------------- fallback masks ----------------
__global__ void mask_kernel(const float* __restrict__ queries, const float* __restrict__ keys,
                            float* __restrict__ qm, float* __restrict__ kb) {
    const int w = threadIdx.x >> 6, lane = threadIdx.x & 63;
    const int row = blockIdx.x * 4 + w;
    const int which = blockIdx.y;
    const float* X = which ? keys : queries;
    const float4* p = (const float4*)&X[(size_t)row * D_];
    float s = 0.f;
#pragma unroll
    for (int i = 0; i < 2; ++i) {
        float4 v = p[lane + 64 * i];
        s += v.x + v.y + v.z + v.w;
    }
#pragma unroll
    for (int m = 1; m < 64; m <<= 1) s += __shfl_xor(s, m);
    if (lane == 0) {
        if (which) kb[row] = (s != 0.0f) ? 0.0f : -3e30f;
        else       qm[row] = (s != 0.0f) ? 1.0f : 0.0f;
    }
}

// ---------------- V transpose (mid/fallback tiers only) ----------------
__global__ void vtrans_kernel(const short* __restrict__ Vb, short* __restrict__ VtG) {
    __shared__ short tile[64][72];
    const int t = threadIdx.x;
    const int kt = blockIdx.x & 15;
    const int h  = (blockIdx.x >> 4) & 7;
    const int b  = blockIdx.x >> 7;
#pragma unroll
    for (int i = 0; i < 2; ++i) {
        int idx = t + i * 256;
        int r = idx >> 3, c8 = idx & 7;
        *(bf16x8*)&tile[((r & 7) << 3) | (r >> 3)][c8 * 8] =
            *(const bf16x8*)&Vb[(size_t)(b * T_ + kt * 64 + r) * D_ + h * 64 + c8 * 8];
    }
    __syncthreads();
#pragma unroll
    for (int i = 0; i < 2; ++i) {
        int idx = t + i * 256;
        int d = idx >> 3, r8 = idx & 7;
        bf16x8 pk;
#pragma unroll
        for (int j = 0; j < 8; ++j) pk[j] = tile[(j << 3) | r8][d];
        *(bf16x8*)&VtG[(size_t)((b * 8 + h) * 64 + d) * T_ + kt * 64 + r8 * 8] = pk;
    }
}

// ---------------- attention helpers ----------------
__device__ __forceinline__ void qk1(f32x4 (&s)[4], const char* Kl,
                                    const bf16x8 (&q)[2], int cl, int g) {
#pragma unroll
    for (int kc = 0; kc < 2; ++kc)
#pragma unroll
        for (int nc = 0; nc < 4; ++nc) {
            bf16x8 a = *(const bf16x8*)(Kl + (nc * 16 + cl) * 128 + (((kc * 4 + g) ^ (cl & 7)) << 4));
            s[nc] = __builtin_amdgcn_mfma_f32_16x16x32_bf16(a, q[kc], s[nc], 0, 0, 0);
        }
}

__device__ __forceinline__ void qk2(f32x4 (&s)[2][4], const char* Kl,
                                    const bf16x8 (&q)[2][2], int cl, int g) {
#pragma unroll
    for (int kc = 0; kc < 2; ++kc)
#pragma unroll
        for (int nc = 0; nc < 4; ++nc) {
            bf16x8 a = *(const bf16x8*)(Kl + (nc * 16 + cl) * 128 + (((kc * 4 + g) ^ (cl & 7)) << 4));
            s[0][nc] = __builtin_amdgcn_mfma_f32_16x16x32_bf16(a, q[0][kc], s[0][nc], 0, 0, 0);
            s[1][nc] = __builtin_amdgcn_mfma_f32_16x16x32_bf16(a, q[1][kc], s[1][nc], 0, 0, 0);
        }
}

#define CSC_ (0.125f * 1.44269504088896f)

// single-tile softmax+PV (round-9 body; l kept lane-partial, reduced in epilogue)
template <bool CAUSAL>
__device__ __forceinline__ void smax1(f32x4 (&s)[4], const f32x4 (&kb4)[4],
                                      f32x4 (&o)[4], float& m, float& l,
                                      int qmk, const char* Vl, int cl, int g) {
    float pmn[4];
#pragma unroll
    for (int nc = 0; nc < 4; ++nc) {
#pragma unroll
        for (int j = 0; j < 4; ++j) {
            float v = fmaf(s[nc][j], CSC_, kb4[nc][j]);
            if (CAUSAL && (nc * 16 + g * 4 + j > qmk)) v = -3e30f;
            s[nc][j] = v;
        }
        pmn[nc] = fmaxf(fmaxf(s[nc][0], s[nc][1]), fmaxf(s[nc][2], s[nc][3]));
    }
    float pm = fmaxf(fmaxf(pmn[0], pmn[1]), fmaxf(pmn[2], pmn[3]));
    pm = fmaxf(pm, __shfl_xor(pm, 16));
    pm = fmaxf(pm, __shfl_xor(pm, 32));
    if (__any(pm > m + 8.f)) {
        float mn = fmaxf(m, pm), cf;
        asm("v_exp_f32 %0, %1" : "=v"(cf) : "v"(m - mn));
        l *= cf;
        m = mn;
#pragma unroll
        for (int j = 0; j < 4; ++j) {
            float cfj = __shfl(cf, g * 4 + j);
#pragma unroll
            for (int dc = 0; dc < 4; ++dc) o[dc][j] *= cfj;
        }
    }
    float ps = 0.f;
#pragma unroll
    for (int nc = 0; nc < 4; ++nc)
#pragma unroll
        for (int j = 0; j < 4; ++j) {
            float p;
            asm("v_exp_f32 %0, %1" : "=v"(p) : "v"(s[nc][j] - m));
            s[nc][j] = p;
            ps += p;
        }
    l += ps;   // lane-partial; cross-lane reduce deferred to epilogue

    unsigned wp[4][2];
#pragma unroll
    for (int nc = 0; nc < 4; ++nc) {
        asm("v_cvt_pk_bf16_f32 %0, %1, %2" : "=v"(wp[nc][0]) : "v"(s[nc][0]), "v"(s[nc][1]));
        asm("v_cvt_pk_bf16_f32 %0, %1, %2" : "=v"(wp[nc][1]) : "v"(s[nc][2]), "v"(s[nc][3]));
    }
    const bool bp = (g & 1);
#pragma unroll
    for (int ks = 0; ks < 2; ++ks) {
        unsigned A0 = wp[2 * ks][0], A1 = wp[2 * ks][1];
        unsigned B0 = wp[2 * ks + 1][0], B1 = wp[2 * ks + 1][1];
        unsigned snd0 = bp ? A0 : B0, snd1 = bp ? A1 : B1;
        unsigned rcv0 = __shfl_xor(snd0, 16), rcv1 = __shfl_xor(snd1, 16);
        union { unsigned u[4]; bf16x8 v; } pa;
        pa.u[0] = bp ? rcv0 : A0;
        pa.u[1] = bp ? rcv1 : A1;
        pa.u[2] = bp ? B0 : rcv0;
        pa.u[3] = bp ? B1 : rcv1;
        const int vg = ks * 4 + (g & 1) * 2 + (g >> 1);
#pragma unroll
        for (int dc = 0; dc < 4; ++dc) {
            bf16x8 vv = *(const bf16x8*)(Vl + (dc * 16 + cl) * 128 + ((vg ^ (cl & 7)) << 4));
            o[dc] = __builtin_amdgcn_mfma_f32_16x16x32_bf16(pa.v, vv, o[dc], 0, 0, 0);
        }
    }
}

// dual-tile softmax+PV: hi (tl=0, never causal here) + lo (tl=1, causal iff CLO).
// Shares V LDS reads between the two q-tiles.
template <bool CLO>
__device__ __forceinline__ void smax2(f32x4 (&s)[2][4], const f32x4 (&kb4)[4],
                                      f32x4 (&o)[2][4], float (&m)[2], float (&l)[2],
                                      int qmkLo, const char* Vl, int cl, int g) {
    float pm[2];
#pragma unroll
    for (int tl = 0; tl < 2; ++tl) {
        float pmn[4];
#pragma unroll
        for (int nc = 0; nc < 4; ++nc) {
#pragma unroll
            for (int j = 0; j < 4; ++j) {
                float v = fmaf(s[tl][nc][j], CSC_, kb4[nc][j]);
                if (tl == 1 && CLO && (nc * 16 + g * 4 + j > qmkLo)) v = -3e30f;
                s[tl][nc][j] = v;
            }
            pmn[nc] = fmaxf(fmaxf(s[tl][nc][0], s[tl][nc][1]), fmaxf(s[tl][nc][2], s[tl][nc][3]));
        }
        float p = fmaxf(fmaxf(pmn[0], pmn[1]), fmaxf(pmn[2], pmn[3]));
        p = fmaxf(p, __shfl_xor(p, 16));
        p = fmaxf(p, __shfl_xor(p, 32));
        pm[tl] = p;
    }
    if (__any((pm[0] > m[0] + 8.f) || (pm[1] > m[1] + 8.f))) {
#pragma unroll
        for (int tl = 0; tl < 2; ++tl) {
            float mn = fmaxf(m[tl], pm[tl]), cf;
            asm("v_exp_f32 %0, %1" : "=v"(cf) : "v"(m[tl] - mn));
            l[tl] *= cf;
            m[tl] = mn;
#pragma unroll
            for (int j = 0; j < 4; ++j) {
                float cfj = __shfl(cf, g * 4 + j);
#pragma unroll
                for (int dc = 0; dc < 4; ++dc) o[tl][dc][j] *= cfj;
            }
        }
    }
    unsigned wp[2][4][2];
#pragma unroll
    for (int tl = 0; tl < 2; ++tl) {
        float ps = 0.f;
#pragma unroll
        for (int nc = 0; nc < 4; ++nc) {
#pragma unroll
            for (int j = 0; j < 4; ++j) {
                float p;
                asm("v_exp_f32 %0, %1" : "=v"(p) : "v"(s[tl][nc][j] - m[tl]));
                s[tl][nc][j] = p;
                ps += p;
            }
            asm("v_cvt_pk_bf16_f32 %0, %1, %2" : "=v"(wp[tl][nc][0]) : "v"(s[tl][nc][0]), "v"(s[tl][nc][1]));
            asm("v_cvt_pk_bf16_f32 %0, %1, %2" : "=v"(wp[tl][nc][1]) : "v"(s[tl][nc][2]), "v"(s[tl][nc][3]));
        }
        l[tl] += ps;   // lane-partial
    }
    const bool bp = (g & 1);
#pragma unroll
    for (int ks = 0; ks < 2; ++ks) {
        union { unsigned u[4]; bf16x8 v; } pa[2];
#pragma unroll
        for (int tl = 0; tl < 2; ++tl) {
            unsigned A0 = wp[tl][2 * ks][0], A1 = wp[tl][2 * ks][1];
            unsigned B0 = wp[tl][2 * ks + 1][0], B1 = wp[tl][2 * ks + 1][1];
            unsigned snd0 = bp ? A0 : B0, snd1 = bp ? A1 : B1;
            unsigned rcv0 = __shfl_xor(snd0, 16), rcv1 = __shfl_xor(snd1, 16);
            pa[tl].u[0] = bp ? rcv0 : A0;
            pa[tl].u[1] = bp ? rcv1 : A1;
            pa[tl].u[2] = bp ? B0 : rcv0;
            pa[tl].u[3] = bp ? B1 : rcv1;
        }
        const int vg = ks * 4 + (g & 1) * 2 + (g >> 1);
#pragma unroll
        for (int dc = 0; dc < 4; ++dc) {
            bf16x8 vv = *(const bf16x8*)(Vl + (dc * 16 + cl) * 128 + ((vg ^ (cl & 7)) << 4));
            o[0][dc] = __builtin_amdgcn_mfma_f32_16x16x32_bf16(pa[0].v, vv, o[0][dc], 0, 0, 0);
            o[1][dc] = __builtin_amdgcn_mfma_f32_16x16x32_bf16(pa[1].v, vv, o[1][dc], 0, 0, 0);
        }
    }
}

// ---------------- flash attention + residual: fused pair (hi=15-pr, lo=pr), one k-loop ----
// lo's k-range nests inside hi's: K/V staged ONCE; shared tiles share K/V LDS reads.
// 1024 blocks x 256 thr = 4 independent blocks/CU (independent barriers preserved).
__global__ __launch_bounds__(256, 4) void attn_kernel(
    const short* __restrict__ Qb, const short* __restrict__ Kb,
    const short* __restrict__ VtG, const float* __restrict__ qmask,
    const float* __restrict__ kbias, const float* __restrict__ queries,
    float* __restrict__ out) {
    __shared__ char KV[2][2][8192];      // [buf][K=0 / V^T=1]
    __shared__ float kbL[1024];
    const int t = threadIdx.x, lane = t & 63, w = t >> 6;
    const int cl = lane & 15, g = lane >> 4;
    const int u = blockIdx.x;
    const int wgid = (u & 7) * 128 + (u >> 3);   // co-XCD grouping for same (b,h)
    const int pr = wgid & 7, h = (wgid >> 3) & 7, b = wgid >> 6;
    const int ntHi = 16 - pr;                    // hi q-tile = 15-pr needs tiles 0..15-pr
    const int qrH = (15 - pr) * 64 + w * 16 + cl;
    const int qrL = pr * 64 + w * 16 + cl;

    const int rS0 = t >> 3,  cS0 = ((t & 7) ^ (rS0 & 7)) * 8;
    const int t2 = t + 256;
    const int rS1 = t2 >> 3, cS1 = ((t2 & 7) ^ (rS1 & 7)) * 8;
    const short* kS0 = Kb  + ((size_t)(b * T_) + rS0) * D_ + h * 64 + cS0;
    const short* kS1 = Kb  + ((size_t)(b * T_) + rS1) * D_ + h * 64 + cS1;
    const short* vS0 = VtG + (size_t)((b * 8 + h) * 64 + rS0) * T_ + cS0;
    const short* vS1 = VtG + (size_t)((b * 8 + h) * 64 + rS1) * T_ + cS1;

    gld_lds16(kbias + b * T_ + t * 4, (char*)kbL + t * 16);

    bf16x8 qb[2][2];
#pragma unroll
    for (int kc = 0; kc < 2; ++kc) {
        qb[0][kc] = *(const bf16x8*)&Qb[(size_t)(b * T_ + qrH) * D_ + h * 64 + kc * 32 + g * 8];
        qb[1][kc] = *(const bf16x8*)&Qb[(size_t)(b * T_ + qrL) * D_ + h * 64 + kc * 32 + g * 8];
    }

    // prologue: stage tile 0 -> buf 0
    gld_lds16(kS0, &KV[0][0][0]    + t * 16);
    gld_lds16(kS1, &KV[0][0][4096] + t * 16);
    gld_lds16(vS0, &KV[0][1][0]    + t * 16);
    gld_lds16(vS1, &KV[0][1][4096] + t * 16);

    f32x4 o[2][4] = {};
    float m[2] = {-3e30f, -3e30f}, l[2] = {0.f, 0.f};
    int tb = 0;

    for (int it = 0; it < ntHi; ++it) {
        __syncthreads();   // implicit vmcnt(0): tile staged; all waves done with tb^1

        f32x4 kb4[4];
#pragma unroll
        for (int nc = 0; nc < 4; ++nc)
            kb4[nc] = *(const f32x4*)((const char*)kbL + it * 256 + nc * 64 + g * 16);

        if (it + 1 < ntHi) {   // prefetch next k-tile into tb^1
            const int kt2 = (it + 1) * 64;
            char* db = &KV[tb ^ 1][0][0];
            gld_lds16(kS0 + (size_t)kt2 * D_, db + t * 16);
            gld_lds16(kS1 + (size_t)kt2 * D_, db + 4096 + t * 16);
            gld_lds16(vS0 + kt2, db + 8192 + t * 16);
            gld_lds16(vS1 + kt2, db + 8192 + 4096 + t * 16);
        }

        const char* Kl = &KV[tb][0][0];
        const char* Vl = &KV[tb][1][0];

        if (it <= pr) {        // shared region: both q-tiles active, K/V reads shared
            f32x4 s2[2][4] = {};
            qk2(s2, Kl, qb, cl, g);
            if (it == pr) smax2<true >(s2, kb4, o, m, l, w * 16 + cl, Vl, cl, g);
            else          smax2<false>(s2, kb4, o, m, l, 0,           Vl, cl, g);
        } else {               // hi-only region
            f32x4 s[4] = {};
            qk1(s, Kl, qb[0], cl, g);
            if (it == ntHi - 1) smax1<true >(s, kb4, o[0], m[0], l[0], w * 16 + cl, Vl, cl, g);
            else                smax1<false>(s, kb4, o[0], m[0], l[0], 0,           Vl, cl, g);
        }
        tb ^= 1;
    }

    // epilogue: reduce lane-partial l, normalize, query mask, residual
#pragma unroll
    for (int tl = 0; tl < 2; ++tl) {
        float lt = l[tl];
        lt += __shfl_xor(lt, 16);
        lt += __shfl_xor(lt, 32);
        float inv = 1.0f / lt;
        const int qt = (tl ? pr : 15 - pr) * 64 + w * 16;
#pragma unroll
        for (int j = 0; j < 4; ++j) {
            float linv = __shfl(inv, g * 4 + j);
            const int q = qt + g * 4 + j;
            const float sc2 = linv * qmask[b * T_ + q];
            const size_t base = (size_t)(b * T_ + q) * D_ + h * 64;
#pragma unroll
            for (int dc = 0; dc < 4; ++dc) {
                const size_t idx = base + dc * 16 + cl;
                out[idx] = o[tl][dc][j] * sc2 + queries[idx];
            }
        }
    }
}

extern "C" void kernel_launch(void* const* d_in, const int* in_sizes, int n_in,
                              void* d_out, int out_size, void* d_ws, size_t ws_size,
                              hipStream_t stream) {
    const float* queries = (const float*)d_in[0];
    const float* keys    = (const float*)d_in[1];
    const float* value   = (const float*)d_in[2];
    const float* Wq      = (const float*)d_in[3];
    const float* bq      = (const float*)d_in[4];
    const float* Wk      = (const float*)d_in[5];
    const float* bk      = (const float*)d_in[6];
    const float* Wv      = (const float*)d_in[7];
    const float* bv      = (const float*)d_in[8];
    float* out = (float*)d_out;

    char* ws = (char*)d_ws;
    const size_t WT_SZ  = (size_t)D_ * D_ * 2;
    const size_t XB_SZ  = (size_t)M_ * D_ * 2;
    const size_t MASKS  = 2 * (size_t)M_ * 4;

    const size_t NEED_FULL = 3 * WT_SZ + 7 * XB_SZ + MASKS;
    const size_t NEED_MID  = 3 * WT_SZ + 6 * XB_SZ + MASKS;

    if (ws_size >= NEED_FULL) {
        short* WtAll = (short*)(ws);
        short* Xbf   = (short*)(ws + 3 * WT_SZ);
        short* QKV   = (short*)(ws + 3 * WT_SZ + 3 * XB_SZ);
        short* Qb = QKV, *Kb = QKV + M_ * D_;
        short* VtG   = (short*)(ws + 3 * WT_SZ + 6 * XB_SZ);
        float* qm    = (float*)(ws + 3 * WT_SZ + 7 * XB_SZ);
        float* kb    = qm + M_;

        prep_kernel<<<dim3(64 + M_ / 4, 3), 256, 0, stream>>>(
            queries, keys, value, Wq, Wk, Wv, Xbf, WtAll, qm, kb);
        proj_gemm_bf<<<1536, 256, 0, stream>>>(Xbf, WtAll, bq, bk, bv, QKV, VtG);
        attn_kernel<<<1024, 256, 0, stream>>>(Qb, Kb, VtG, qm, kb, queries, out);
    } else if (ws_size >= NEED_MID) {
        short* WtAll = (short*)(ws);
        short* Xbf   = (short*)(ws + 3 * WT_SZ);
        short* QKV   = (short*)(ws + 3 * WT_SZ + 3 * XB_SZ);
        short* Qb = QKV, *Kb = QKV + M_ * D_, *Vb = QKV + 2 * (size_t)M_ * D_;
        short* VtG   = Xbf;
        float* qm    = (float*)(ws + 3 * WT_SZ + 6 * XB_SZ);
        float* kb    = qm + M_;

        prep_kernel<<<dim3(64 + M_ / 4, 3), 256, 0, stream>>>(
            queries, keys, value, Wq, Wk, Wv, Xbf, WtAll, qm, kb);
        proj_gemm_bf<<<1536, 256, 0, stream>>>(Xbf, WtAll, bq, bk, bv, QKV, nullptr);
        vtrans_kernel<<<B_ * H_ * (T_ / 64), 256, 0, stream>>>(Vb, VtG);
        attn_kernel<<<1024, 256, 0, stream>>>(Qb, Kb, VtG, qm, kb, queries, out);
    } else {
        short* WtAll = (short*)(ws);
        short* Qb  = (short*)(ws + 3 * WT_SZ);
        short* Kb  = (short*)(ws + 3 * WT_SZ + XB_SZ);
        short* Vb  = (short*)(ws + 3 * WT_SZ + 2 * XB_SZ);
        short* VtG = (short*)(ws + 3 * WT_SZ + 3 * XB_SZ);
        float* qm  = (float*)(ws + 3 * WT_SZ + 4 * XB_SZ);
        float* kb  = qm + M_;

        prep_kernel<<<dim3(64, 3), 256, 0, stream>>>(
            queries, keys, value, Wq, Wk, Wv, nullptr, WtAll, qm, kb);
        mask_kernel<<<dim3(M_ / 4, 2), 256, 0, stream>>>(queries, keys, qm, kb);
        proj_gemm<<<dim3(M_ / 128, D_ / 128, 3), 256, 0, stream>>>(
            queries, keys, value, WtAll, bq, bk, bv, Qb, Kb, Vb);
        vtrans_kernel<<<B_ * H_ * (T_ / 64), 256, 0, stream>>>(Vb, VtG);
        attn_kernel<<<1024, 256, 0, stream>>>(Qb, Kb, VtG, qm, kb, queries, out);
    }
}

// Round 14
// 102.177 us; speedup vs baseline: 2.6771x; 2.6771x over previous
//
#include <hip/hip_runtime.h>
#include <hip/hip_bf16.h>

#define B_ 16
#define T_ 1024
#define D_ 512
#define H_ 8
#define M_ (B_ * T_)

typedef __attribute__((ext_vector_type(4))) float f32x4;
typedef __attribute__((ext_vector_type(8))) short bf16x8;
typedef __attribute__((ext_vector_type(4))) short bf16x4;

__device__ __forceinline__ void gld_lds16(const void* g, void* l) {
    __builtin_amdgcn_global_load_lds((const __attribute__((address_space(1))) void*)g,
                                     (__attribute__((address_space(3))) void*)l, 16, 0, 0);
}

__device__ __forceinline__ short f2bf(float f) {
    union { float f; unsigned u; } v; v.f = f;
    unsigned r = v.u + 0x7FFF + ((v.u >> 16) & 1);
    return (short)(r >> 16);
}

// ---------------- fused prep: wtrans (blocks 0..63) + cvt/masks (blocks 64..4159) ----------
__global__ void prep_kernel(const float* __restrict__ q, const float* __restrict__ k,
                            const float* __restrict__ v,
                            const float* __restrict__ Wq, const float* __restrict__ Wk,
                            const float* __restrict__ Wv,
                            short* __restrict__ Xbf, short* __restrict__ WtAll,
                            float* __restrict__ qm, float* __restrict__ kb) {
    __shared__ float tile[64][65];
    const int t = threadIdx.x;
    const int mat = blockIdx.y;
    if (blockIdx.x < 64) {
        const float* W = (mat == 0) ? Wq : (mat == 1) ? Wk : Wv;
        short* Wt = WtAll + (size_t)mat * D_ * D_;
        const int kt = ((int)blockIdx.x >> 3) * 64;
        const int nt = ((int)blockIdx.x & 7) * 64;
#pragma unroll
        for (int i = 0; i < 4; ++i) {
            int idx = t + i * 256;
            int r = idx >> 4, c4 = idx & 15;
            float4 vv = *(const float4*)&W[(kt + r) * D_ + nt + c4 * 4];
            tile[r][c4 * 4 + 0] = vv.x; tile[r][c4 * 4 + 1] = vv.y;
            tile[r][c4 * 4 + 2] = vv.z; tile[r][c4 * 4 + 3] = vv.w;
        }
        __syncthreads();
#pragma unroll
        for (int i = 0; i < 2; ++i) {
            int idx = t + i * 256;
            int nr = idx >> 3, c8 = idx & 7;
            bf16x8 pk;
#pragma unroll
            for (int j = 0; j < 8; ++j) pk[j] = f2bf(tile[c8 * 8 + j][nr]);
            *(bf16x8*)&Wt[(nt + nr) * D_ + kt + c8 * 8] = pk;
        }
    } else {
        const int w = t >> 6, lane = t & 63;
        const int row = ((int)blockIdx.x - 64) * 4 + w;
        const float* X = (mat == 0) ? q : (mat == 1) ? k : v;
        short* O = Xbf + (size_t)mat * M_ * D_;
        const float4* p = (const float4*)&X[(size_t)row * D_];
        float4 v0 = p[lane], v1 = p[lane + 64];
        float s = v0.x + v0.y + v0.z + v0.w + v1.x + v1.y + v1.z + v1.w;
#pragma unroll
        for (int m = 1; m < 64; m <<= 1) s += __shfl_xor(s, m);
        bf16x4 p0, p1;
        p0[0] = f2bf(v0.x); p0[1] = f2bf(v0.y); p0[2] = f2bf(v0.z); p0[3] = f2bf(v0.w);
        p1[0] = f2bf(v1.x); p1[1] = f2bf(v1.y); p1[2] = f2bf(v1.z); p1[3] = f2bf(v1.w);
        *(bf16x4*)&O[(size_t)row * D_ + lane * 4] = p0;
        *(bf16x4*)&O[(size_t)row * D_ + 256 + lane * 4] = p1;
        if (lane == 0) {
            if (mat == 0) qm[row] = (s != 0.0f) ? 1.0f : 0.0f;
            else if (mat == 1) kb[row] = (s != 0.0f) ? 0.0f : -3e30f;
        }
    }
}

// ---------------- projection GEMM, pure bf16 (m97 structure, gld_lds staging) ----------------
__global__ __launch_bounds__(256) void proj_gemm_bf(
    const short* __restrict__ Xbf, const short* __restrict__ WtAll,
    const float* __restrict__ bq, const float* __restrict__ bk, const float* __restrict__ bv,
    short* __restrict__ QKV, short* __restrict__ VtG) {
    __shared__ char As[16384];
    __shared__ char Bs[16384];
    const int t = threadIdx.x;
    const int u = blockIdx.x;
    const int wgid = (u & 7) * 192 + (u >> 3);
    const int mat = wgid >> 9;
    const int r = wgid & 511;
    const int m0 = (r >> 2) << 7, n0 = (r & 3) << 7;
    const short* X  = Xbf + (size_t)mat * M_ * D_;
    const short* Wt = WtAll + (size_t)mat * D_ * D_;
    const float* bias = (mat == 0) ? bq : (mat == 1) ? bk : bv;
    short* dst = QKV + (size_t)mat * M_ * D_;
    const int lane = t & 63, w = t >> 6;
    const int wr = w >> 1, wc = w & 1;
    const int cl = lane & 15, g = lane >> 4;

    const int r0 = t >> 3, c0 = ((t & 7) ^ (r0 & 7)) * 8;
    const short* sA = X  + (size_t)(m0 + r0) * D_ + c0;
    const short* sB = Wt + (size_t)(n0 + r0) * D_ + c0;

    f32x4 acc[4][4] = {};
#pragma unroll
    for (int i = 0; i < 4; ++i) {
        gld_lds16(sA + (size_t)(32 * i) * D_, As + t * 16 + i * 4096);
        gld_lds16(sB + (size_t)(32 * i) * D_, Bs + t * 16 + i * 4096);
    }
    for (int kt = 0; kt < D_; kt += 64) {
        __syncthreads();
#pragma unroll
        for (int ks = 0; ks < 2; ++ks) {
            bf16x8 a[4], b[4];
#pragma unroll
            for (int m = 0; m < 4; ++m)
                a[m] = *(const bf16x8*)(As + (wr * 64 + m * 16 + cl) * 128 + (((ks * 4 + g) ^ (cl & 7)) << 4));
#pragma unroll
            for (int n = 0; n < 4; ++n)
                b[n] = *(const bf16x8*)(Bs + (wc * 64 + n * 16 + cl) * 128 + (((ks * 4 + g) ^ (cl & 7)) << 4));
#pragma unroll
            for (int m = 0; m < 4; ++m)
#pragma unroll
                for (int n = 0; n < 4; ++n)
                    acc[m][n] = __builtin_amdgcn_mfma_f32_16x16x32_bf16(a[m], b[n], acc[m][n], 0, 0, 0);
        }
        __syncthreads();
        if (kt + 64 < D_) {
            const int k2 = kt + 64;
#pragma unroll
            for (int i = 0; i < 4; ++i) {
                gld_lds16(sA + (size_t)(32 * i) * D_ + k2, As + t * 16 + i * 4096);
                gld_lds16(sB + (size_t)(32 * i) * D_ + k2, Bs + t * 16 + i * 4096);
            }
        }
    }
    if (VtG != nullptr && mat == 2) {
        const int bb = m0 >> 10, tl0 = m0 & 1023;
#pragma unroll
        for (int n = 0; n < 4; ++n) {
            const int col = n0 + wc * 64 + n * 16 + cl;
            const int h = col >> 6, dh = col & 63;
            short* vrow = VtG + ((size_t)(bb * 8 + h) * 64 + dh) * T_;
            const float bv2 = bias[col];
#pragma unroll
            for (int m = 0; m < 4; ++m) {
                const int tl = tl0 + wr * 64 + m * 16 + g * 4;
                bf16x4 pk;
#pragma unroll
                for (int j = 0; j < 4; ++j) pk[j] = f2bf(acc[m][n][j] + bv2);
                *(bf16x4*)&vrow[tl] = pk;
            }
        }
    } else {
#pragma unroll
        for (int n = 0; n < 4; ++n) {
            int col = n0 + wc * 64 + n * 16 + cl;
            float bv2 = bias[col];
#pragma unroll
            for (int m = 0; m < 4; ++m) {
                int rowb = m0 + wr * 64 + m * 16 + g * 4;
#pragma unroll
                for (int j = 0; j < 4; ++j)
                    dst[(size_t)(rowb + j) * D_ + col] = f2bf(acc[m][n][j] + bv2);
            }
        }
    }
}

// ---------------- fallback projection GEMM (fp32 X, in-kernel conversion) ----------------
__global__ __launch_bounds__(256) void proj_gemm(
    const float* __restrict__ Xq, const float* __restrict__ Xk, const float* __restrict__ Xv,
    const short* __restrict__ WtAll,
    const float* __restrict__ bq, const float* __restrict__ bk, const float* __restrict__ bv,
    short* __restrict__ Qb, short* __restrict__ Kb, short* __restrict__ Vb) {
    __shared__ short As2[128][72];
    __shared__ short Bs2[128][72];
    const int t = threadIdx.x;
    const int mat = blockIdx.z;
    const float* X = (mat == 0) ? Xq : (mat == 1) ? Xk : Xv;
    const short* Wt = WtAll + (size_t)mat * D_ * D_;
    const float* bias = (mat == 0) ? bq : (mat == 1) ? bk : bv;
    short* dst = (mat == 0) ? Qb : (mat == 1) ? Kb : Vb;
    const int m0 = blockIdx.x * 128, n0 = blockIdx.y * 128;
    const int lane = t & 63, w = t >> 6;
    const int wr = w >> 1, wc = w & 1;
    const int cl = lane & 15, g = lane >> 4;
    f32x4 acc[4][4] = {};
    for (int kt = 0; kt < D_; kt += 64) {
#pragma unroll
        for (int i = 0; i < 8; ++i) {
            int idx = t + 256 * i;
            int r = idx >> 4, c4 = idx & 15;
            float4 v = *(const float4*)&X[(size_t)(m0 + r) * D_ + kt + c4 * 4];
            bf16x4 pk;
            pk[0] = f2bf(v.x); pk[1] = f2bf(v.y); pk[2] = f2bf(v.z); pk[3] = f2bf(v.w);
            *(bf16x4*)&As2[r][c4 * 4] = pk;
        }
#pragma unroll
        for (int i = 0; i < 4; ++i) {
            int idx = t + 256 * i;
            int r = idx >> 3, c8 = idx & 7;
            *(bf16x8*)&Bs2[r][c8 * 8] = *(const bf16x8*)&Wt[(size_t)(n0 + r) * D_ + kt + c8 * 8];
        }
        __syncthreads();
#pragma unroll
        for (int ks = 0; ks < 2; ++ks) {
            bf16x8 a[4], b[4];
#pragma unroll
            for (int m = 0; m < 4; ++m)
                a[m] = *(const bf16x8*)&As2[wr * 64 + m * 16 + cl][ks * 32 + g * 8];
#pragma unroll
            for (int n = 0; n < 4; ++n)
                b[n] = *(const bf16x8*)&Bs2[wc * 64 + n * 16 + cl][ks * 32 + g * 8];
#pragma unroll
            for (int m = 0; m < 4; ++m)
#pragma unroll
                for (int n = 0; n < 4; ++n)
                    acc[m][n] = __builtin_amdgcn_mfma_f32_16x16x32_bf16(a[m], b[n], acc[m][n], 0, 0, 0);
        }
        __syncthreads();
    }
#pragma unroll
    for (int n = 0; n < 4; ++n) {
        int col = n0 + wc * 64 + n * 16 + cl;
        float bv2 = bias[col];
#pragma unroll
        for (int m = 0; m < 4; ++m) {
            int rowb = m0 + wr * 64 + m * 16 + g * 4;
#pragma unroll
            for (int j = 0; j < 4; ++j)
                dst[(size_t)(rowb + j) * D_ + col] = f2bf(acc[m][n][j] + bv2);
        }
    }
}

// ---------------- fallback masks ----------------
__global__ void mask_kernel(const float* __restrict__ queries, const float* __restrict__ keys,
                            float* __restrict__ qm, float* __restrict__ kb) {
    const int w = threadIdx.x >> 6, lane = threadIdx.x & 63;
    const int row = blockIdx.x * 4 + w;
    const int which = blockIdx.y;
    const float* X = which ? keys : queries;
    const float4* p = (const float4*)&X[(size_t)row * D_];
    float s = 0.f;
#pragma unroll
    for (int i = 0; i < 2; ++i) {
        float4 v = p[lane + 64 * i];
        s += v.x + v.y + v.z + v.w;
    }
#pragma unroll
    for (int m = 1; m < 64; m <<= 1) s += __shfl_xor(s, m);
    if (lane == 0) {
        if (which) kb[row] = (s != 0.0f) ? 0.0f : -3e30f;
        else       qm[row] = (s != 0.0f) ? 1.0f : 0.0f;
    }
}

// ---------------- V transpose (mid/fallback tiers only) ----------------
__global__ void vtrans_kernel(const short* __restrict__ Vb, short* __restrict__ VtG) {
    __shared__ short tile[64][72];
    const int t = threadIdx.x;
    const int kt = blockIdx.x & 15;
    const int h  = (blockIdx.x >> 4) & 7;
    const int b  = blockIdx.x >> 7;
#pragma unroll
    for (int i = 0; i < 2; ++i) {
        int idx = t + i * 256;
        int r = idx >> 3, c8 = idx & 7;
        *(bf16x8*)&tile[((r & 7) << 3) | (r >> 3)][c8 * 8] =
            *(const bf16x8*)&Vb[(size_t)(b * T_ + kt * 64 + r) * D_ + h * 64 + c8 * 8];
    }
    __syncthreads();
#pragma unroll
    for (int i = 0; i < 2; ++i) {
        int idx = t + i * 256;
        int d = idx >> 3, r8 = idx & 7;
        bf16x8 pk;
#pragma unroll
        for (int j = 0; j < 8; ++j) pk[j] = tile[(j << 3) | r8][d];
        *(bf16x8*)&VtG[(size_t)((b * 8 + h) * 64 + d) * T_ + kt * 64 + r8 * 8] = pk;
    }
}

// ---------------- attention helpers ----------------
__device__ __forceinline__ void qk_mfma(f32x4 (&s)[4], const char* Kl,
                                        const bf16x8 (&q)[2], int cl, int g) {
#pragma unroll
    for (int kc = 0; kc < 2; ++kc)
#pragma unroll
        for (int nc = 0; nc < 4; ++nc) {
            bf16x8 a = *(const bf16x8*)(Kl + (nc * 16 + cl) * 128 + (((kc * 4 + g) ^ (cl & 7)) << 4));
            s[nc] = __builtin_amdgcn_mfma_f32_16x16x32_bf16(a, q[kc], s[nc], 0, 0, 0);
        }
}

// scale+bias (+causal), online softmax, in-register P exchange, PV.
// round-12 body + lane-partial l deferral (proven correct in round 13):
// cf is uniform across lanes {cl, cl+16, cl+32, cl+48}, so partial l sums rescale correctly.
template <bool CAUSAL>
__device__ __forceinline__ void smax_pv(f32x4 (&s)[4], const f32x4 (&kb4)[4],
                                        f32x4 (&o)[4], float& m, float& l,
                                        int qmk, const char* Vl, int cl, int g) {
    const float csc = 0.125f * 1.44269504088896f;   // 1/sqrt(64) * log2(e)
    float pm = -3e30f;
#pragma unroll
    for (int nc = 0; nc < 4; ++nc)
#pragma unroll
        for (int j = 0; j < 4; ++j) {
            float v = fmaf(s[nc][j], csc, kb4[nc][j]);
            if (CAUSAL && (nc * 16 + g * 4 + j > qmk)) v = -3e30f;
            s[nc][j] = v;
            pm = fmaxf(pm, v);
        }
    pm = fmaxf(pm, __shfl_xor(pm, 16));
    pm = fmaxf(pm, __shfl_xor(pm, 32));
    // defer-max: skip O/l rescale while max grows < 8 (exp2 domain)
    if (__any(pm > m + 8.f)) {
        float mn = fmaxf(m, pm), cf;
        asm("v_exp_f32 %0, %1" : "=v"(cf) : "v"(m - mn));
        l *= cf;
        m = mn;
#pragma unroll
        for (int j = 0; j < 4; ++j) {
            float cfj = __shfl(cf, g * 4 + j);
#pragma unroll
            for (int dc = 0; dc < 4; ++dc) o[dc][j] *= cfj;
        }
    }
    float ps = 0.f;
#pragma unroll
    for (int nc = 0; nc < 4; ++nc)
#pragma unroll
        for (int j = 0; j < 4; ++j) {
            float p;
            asm("v_exp_f32 %0, %1" : "=v"(p) : "v"(s[nc][j] - m));
            s[nc][j] = p;
            ps += p;
        }
    l += ps;   // lane-partial; cross-lane reduce deferred to epilogue

    // pack P -> bf16 words w[nc][p] = (k = nc*16+g*4+2p, +1)
    unsigned wp[4][2];
#pragma unroll
    for (int nc = 0; nc < 4; ++nc) {
        asm("v_cvt_pk_bf16_f32 %0, %1, %2" : "=v"(wp[nc][0]) : "v"(s[nc][0]), "v"(s[nc][1]));
        asm("v_cvt_pk_bf16_f32 %0, %1, %2" : "=v"(wp[nc][1]) : "v"(s[nc][2]), "v"(s[nc][3]));
    }
    // P-exchange: round-8/9-proven shfl form
    const bool bp = (g & 1);
#pragma unroll
    for (int ks = 0; ks < 2; ++ks) {
        unsigned A0 = wp[2 * ks][0], A1 = wp[2 * ks][1];
        unsigned B0 = wp[2 * ks + 1][0], B1 = wp[2 * ks + 1][1];
        unsigned snd0 = bp ? A0 : B0, snd1 = bp ? A1 : B1;
        unsigned rcv0 = __shfl_xor(snd0, 16), rcv1 = __shfl_xor(snd1, 16);
        union { unsigned u[4]; bf16x8 v; } pa;
        pa.u[0] = bp ? rcv0 : A0;
        pa.u[1] = bp ? rcv1 : A1;
        pa.u[2] = bp ? B0 : rcv0;
        pa.u[3] = bp ? B1 : rcv1;
        const int vg = ks * 4 + (g & 1) * 2 + (g >> 1);
#pragma unroll
        for (int dc = 0; dc < 4; ++dc) {
            bf16x8 vv = *(const bf16x8*)(Vl + (dc * 16 + cl) * 128 + ((vg ^ (cl & 7)) << 4));
            o[dc] = __builtin_amdgcn_mfma_f32_16x16x32_bf16(pa.v, vv, o[dc], 0, 0, 0);
        }
    }
}

// ---------------- flash attention + residual (round-12 proven structure) ----------------
__global__ __launch_bounds__(256, 4) void attn_kernel(
    const short* __restrict__ Qb, const short* __restrict__ Kb,
    const short* __restrict__ VtG, const float* __restrict__ qmask,
    const float* __restrict__ kbias, const float* __restrict__ queries,
    float* __restrict__ out) {
    __shared__ char KV[2][2][8192];      // [buf][K=0 / V^T=1]
    __shared__ float kbL[1024];          // key-bias row for this b (staged once)
    const int t = threadIdx.x, lane = t & 63, w = t >> 6;
    const int cl = lane & 15, g = lane >> 4;
    const int u = blockIdx.x;
    const int wgid = (u & 7) * 128 + (u >> 3);   // XCD grouping: same-(b,h) blocks co-XCD
    const int pr = wgid & 7, h = (wgid >> 3) & 7, b = wgid >> 6;

    const int rS0 = t >> 3,  cS0 = ((t & 7) ^ (rS0 & 7)) * 8;
    const int t2 = t + 256;
    const int rS1 = t2 >> 3, cS1 = ((t2 & 7) ^ (rS1 & 7)) * 8;
    const short* kS0 = Kb  + ((size_t)(b * T_) + rS0) * D_ + h * 64 + cS0;
    const short* kS1 = Kb  + ((size_t)(b * T_) + rS1) * D_ + h * 64 + cS1;
    const short* vS0 = VtG + (size_t)((b * 8 + h) * 64 + rS0) * T_ + cS0;
    const short* vS1 = VtG + (size_t)((b * 8 + h) * 64 + rS1) * T_ + cS1;

    gld_lds16(kbias + b * T_ + t * 4, (char*)kbL + t * 16);

    int tb = 0;
#pragma unroll
    for (int pass = 0; pass < 2; ++pass) {
        const int qtile = pass ? pr : 15 - pr;
        const int nt = qtile + 1;
        const int qr = qtile * 64 + w * 16 + cl;

        bf16x8 qb[2];
#pragma unroll
        for (int kc = 0; kc < 2; ++kc)
            qb[kc] = *(const bf16x8*)&Qb[(size_t)(b * T_ + qr) * D_ + h * 64 + kc * 32 + g * 8];

        gld_lds16(kS0, &KV[tb][0][0]    + t * 16);
        gld_lds16(kS1, &KV[tb][0][4096] + t * 16);
        gld_lds16(vS0, &KV[tb][1][0]    + t * 16);
        gld_lds16(vS1, &KV[tb][1][4096] + t * 16);

        f32x4 o[4] = {};
        float m = -3e30f, l = 0.f;

        for (int it = 0; it < nt; ++it) {
            __syncthreads();

            f32x4 kb4[4];
#pragma unroll
            for (int nc = 0; nc < 4; ++nc)
                kb4[nc] = *(const f32x4*)((const char*)kbL + it * 256 + nc * 64 + g * 16);

            if (it + 1 < nt) {
                const int kt2 = (it + 1) * 64;
                char* db = &KV[tb ^ 1][0][0];
                gld_lds16(kS0 + (size_t)kt2 * D_, db + t * 16);
                gld_lds16(kS1 + (size_t)kt2 * D_, db + 4096 + t * 16);
                gld_lds16(vS0 + kt2, db + 8192 + t * 16);
                gld_lds16(vS1 + kt2, db + 8192 + 4096 + t * 16);
            }

            const char* Kl = &KV[tb][0][0];
            const char* Vl = &KV[tb][1][0];

            f32x4 s[4] = {};
            qk_mfma(s, Kl, qb, cl, g);
            if (it == nt - 1) smax_pv<true >(s, kb4, o, m, l, w * 16 + cl, Vl, cl, g);
            else              smax_pv<false>(s, kb4, o, m, l, 0,           Vl, cl, g);
            tb ^= 1;
        }

        // epilogue: reduce lane-partial l, normalize, query mask, residual
        float lt = l;
        lt += __shfl_xor(lt, 16);
        lt += __shfl_xor(lt, 32);
        float inv = 1.0f / lt;
#pragma unroll
        for (int j = 0; j < 4; ++j) {
            float linv = __shfl(inv, g * 4 + j);
            const int q = qtile * 64 + w * 16 + g * 4 + j;
            const float sc2 = linv * qmask[b * T_ + q];
            const size_t base = (size_t)(b * T_ + q) * D_ + h * 64;
#pragma unroll
            for (int dc = 0; dc < 4; ++dc) {
                const size_t idx = base + dc * 16 + cl;
                out[idx] = o[dc][j] * sc2 + queries[idx];
            }
        }
    }
}

extern "C" void kernel_launch(void* const* d_in, const int* in_sizes, int n_in,
                              void* d_out, int out_size, void* d_ws, size_t ws_size,
                              hipStream_t stream) {
    const float* queries = (const float*)d_in[0];
    const float* keys    = (const float*)d_in[1];
    const float* value   = (const float*)d_in[2];
    const float* Wq      = (const float*)d_in[3];
    const float* bq      = (const float*)d_in[4];
    const float* Wk      = (const float*)d_in[5];
    const float* bk      = (const float*)d_in[6];
    const float* Wv      = (const float*)d_in[7];
    const float* bv      = (const float*)d_in[8];
    float* out = (float*)d_out;

    char* ws = (char*)d_ws;
    const size_t WT_SZ  = (size_t)D_ * D_ * 2;
    const size_t XB_SZ  = (size_t)M_ * D_ * 2;
    const size_t MASKS  = 2 * (size_t)M_ * 4;

    const size_t NEED_FULL = 3 * WT_SZ + 7 * XB_SZ + MASKS;
    const size_t NEED_MID  = 3 * WT_SZ + 6 * XB_SZ + MASKS;

    if (ws_size >= NEED_FULL) {
        short* WtAll = (short*)(ws);
        short* Xbf   = (short*)(ws + 3 * WT_SZ);
        short* QKV   = (short*)(ws + 3 * WT_SZ + 3 * XB_SZ);
        short* Qb = QKV, *Kb = QKV + M_ * D_;
        short* VtG   = (short*)(ws + 3 * WT_SZ + 6 * XB_SZ);
        float* qm    = (float*)(ws + 3 * WT_SZ + 7 * XB_SZ);
        float* kb    = qm + M_;

        prep_kernel<<<dim3(64 + M_ / 4, 3), 256, 0, stream>>>(
            queries, keys, value, Wq, Wk, Wv, Xbf, WtAll, qm, kb);
        proj_gemm_bf<<<1536, 256, 0, stream>>>(Xbf, WtAll, bq, bk, bv, QKV, VtG);
        attn_kernel<<<1024, 256, 0, stream>>>(Qb, Kb, VtG, qm, kb, queries, out);
    } else if (ws_size >= NEED_MID) {
        short* WtAll = (short*)(ws);
        short* Xbf   = (short*)(ws + 3 * WT_SZ);
        short* QKV   = (short*)(ws + 3 * WT_SZ + 3 * XB_SZ);
        short* Qb = QKV, *Kb = QKV + M_ * D_, *Vb = QKV + 2 * (size_t)M_ * D_;
        short* VtG   = Xbf;
        float* qm    = (float*)(ws + 3 * WT_SZ + 6 * XB_SZ);
        float* kb    = qm + M_;

        prep_kernel<<<dim3(64 + M_ / 4, 3), 256, 0, stream>>>(
            queries, keys, value, Wq, Wk, Wv, Xbf, WtAll, qm, kb);
        proj_gemm_bf<<<1536, 256, 0, stream>>>(Xbf, WtAll, bq, bk, bv, QKV, nullptr);
        vtrans_kernel<<<B_ * H_ * (T_ / 64), 256, 0, stream>>>(Vb, VtG);
        attn_kernel<<<1024, 256, 0, stream>>>(Qb, Kb, VtG, qm, kb, queries, out);
    } else {
        short* WtAll = (short*)(ws);
        short* Qb  = (short*)(ws + 3 * WT_SZ);
        short* Kb  = (short*)(ws + 3 * WT_SZ + XB_SZ);
        short* Vb  = (short*)(ws + 3 * WT_SZ + 2 * XB_SZ);
        short* VtG = (short*)(ws + 3 * WT_SZ + 3 * XB_SZ);
        float* qm  = (float*)(ws + 3 * WT_SZ + 4 * XB_SZ);
        float* kb  = qm + M_;

        prep_kernel<<<dim3(64, 3), 256, 0, stream>>>(
            queries, keys, value, Wq, Wk, Wv, nullptr, WtAll, qm, kb);
        mask_kernel<<<dim3(M_ / 4, 2), 256, 0, stream>>>(queries, keys, qm, kb);
        proj_gemm<<<dim3(M_ / 128, D_ / 128, 3), 256, 0, stream>>>(
            queries, keys, value, WtAll, bq, bk, bv, Qb, Kb, Vb);
        vtrans_kernel<<<B_ * H_ * (T_ / 64), 256, 0, stream>>>(Vb, VtG);
        attn_kernel<<<1024, 256, 0, stream>>>(Qb, Kb, VtG, qm, kb, queries, out);
    }
}